// Round 7
// baseline (325.877 us; speedup 1.0000x reference)
//
#include <hip/hip_runtime.h>

#define E_ 8
#define O_ 256
#define I_ 128
#define B_ 32
#define H_ 56
#define W_ 56
#define HP 58
#define HW (H_*W_)
#define KK 9
#define OI (O_*I_)

#define NROW 4          // pixel rows per n-tile
#define NPIX 224        // NROW*56
#define PPIX 348        // (NROW+2)*58 patch pixels

typedef __attribute__((ext_vector_type(8))) short short8;
typedef __attribute__((ext_vector_type(4))) float float4_;

// ws layout (bytes)
#define XP_ELEMS (B_*HP*HP*I_)                   // padded NHWC bf16
#define POOL_OFF ((size_t)XP_ELEMS*2)            // 27,557,888
#define R_OFF    (POOL_OFF + (size_t)B_*H_*I_*4) // pooled_part: 917,504 B
#define CWT_OFF  (R_OFF + (size_t)B_*E_*4)

__device__ __forceinline__ unsigned short f2bf(float f) {
  union { float f; unsigned u; } v; v.f = f;
  unsigned r = v.u + 0x7FFFu + ((v.u >> 16) & 1u);
  return (unsigned short)(r >> 16);
}

__device__ __forceinline__ void gload16(const unsigned short* g, unsigned short* l) {
  __builtin_amdgcn_global_load_lds(
      (const __attribute__((address_space(1))) unsigned int*)g,
      (__attribute__((address_space(3))) unsigned int*)l, 16, 0, 0);
}

// ---------------- K1: NCHW f32 -> padded NHWC bf16, + per-row channel sums ----------------
__global__ void k1_pool_pack(const float* __restrict__ x,
                             unsigned short* __restrict__ xp,
                             float* __restrict__ pooled_part) {
  __shared__ float lds[I_*57];
  const int h = blockIdx.x, b = blockIdx.y, tid = threadIdx.x;
  const float* xb = x + (size_t)b*I_*HW + h*W_;
  for (int idx = tid; idx < I_*14; idx += 256) {
    int ic = idx / 14, w4 = (idx - ic*14)*4;
    float4_ v = *(const float4_*)(xb + (size_t)ic*HW + w4);
    lds[ic*57 + w4 + 0] = v[0];
    lds[ic*57 + w4 + 1] = v[1];
    lds[ic*57 + w4 + 2] = v[2];
    lds[ic*57 + w4 + 3] = v[3];
  }
  __syncthreads();
  if (tid < I_) {
    float s = 0.f;
    #pragma unroll 8
    for (int wv = 0; wv < W_; ++wv) s += lds[tid*57 + wv];
    pooled_part[(size_t)(b*H_ + h)*I_ + tid] = s;   // no atomics, no memset
  }
  unsigned short* xrow = xp + ((size_t)(b*HP + h + 1)*HP)*I_;
  for (int idx2 = tid; idx2 < W_*(I_/2); idx2 += 256) {
    int wv = idx2 >> 6, ic2 = idx2 & 63;
    unsigned short u0 = f2bf(lds[(ic2*2)*57 + wv]);
    unsigned short u1 = f2bf(lds[(ic2*2+1)*57 + wv]);
    *(unsigned*)&xrow[(wv+1)*I_ + ic2*2] = (unsigned)u0 | ((unsigned)u1 << 16);
  }
  if (tid < I_) {           // pad columns 0 and 57 of this row
    xrow[0*I_ + tid] = 0;
    xrow[57*I_ + tid] = 0;
  }
  if (h == 0) {             // pad row 0
    unsigned short* r0 = xp + (size_t)(b*HP)*HP*I_;
    for (int idx = tid; idx < HP*I_; idx += 256) r0[idx] = 0;
  }
  if (h == H_-1) {          // pad row 57
    unsigned short* r57 = xp + (size_t)((b*HP + 57)*HP)*I_;
    for (int idx = tid; idx < HP*I_; idx += 256) r57[idx] = 0;
  }
}

// ---------------- K2: reduce partials + routing MLP + softmax (fp32 exact) ----------------
__global__ void k2_route(const float* __restrict__ pooled_part,
                         const float* __restrict__ w1, const float* __restrict__ b1,
                         const float* __restrict__ w2, const float* __restrict__ b2,
                         float* __restrict__ r) {
  __shared__ float p[I_];
  __shared__ float hh[32];
  __shared__ float lg[8];
  const int b = blockIdx.x, tid = threadIdx.x;
  if (tid < I_) {
    float s = 0.f;
    for (int h = 0; h < H_; ++h) s += pooled_part[(size_t)(b*H_ + h)*I_ + tid];
    p[tid] = s * (1.f/HW);
  }
  __syncthreads();
  if (tid < 32) {
    float s = b1[tid];
    for (int i = 0; i < I_; ++i) s += p[i]*w1[tid*I_ + i];
    hh[tid] = s > 0.f ? s : 0.f;
  }
  __syncthreads();
  if (tid < 8) {
    float s = b2[tid];
    for (int j = 0; j < 32; ++j) s += hh[j]*w2[tid*32 + j];
    lg[tid] = s;
  }
  __syncthreads();
  if (tid == 0) {
    float m = lg[0];
    for (int e = 1; e < 8; ++e) m = fmaxf(m, lg[e]);
    float ex[8], sum = 0.f;
    for (int e = 0; e < 8; ++e) { ex[e] = expf(lg[e]-m); sum += ex[e]; }
    float inv = 1.f/sum;
    for (int e = 0; e < 8; ++e) r[b*8 + e] = ex[e]*inv;
  }
}

// ---------------- K3: combine expert weights -> cwT[b][tap][o][ic] bf16 ----------------
#define WLS 132   // padded stride (132 % 32 = 4 -> conflict-free float4 reads)
__global__ void k3_combine(const float* __restrict__ weight, const float* __restrict__ r,
                           unsigned short* __restrict__ cwT) {
  __shared__ float wl[E_*9*WLS];   // 38,016 B
  __shared__ float rl[16*E_];
  const int o = blockIdx.x, tid = threadIdx.x;
  const int b0 = blockIdx.y * 16;
  if (tid < 16*E_) rl[tid] = r[b0*E_ + tid];
  for (int e = 0; e < E_; ++e) {
    const float* wg = weight + (size_t)(e*O_ + o)*1152;
    for (int idx = tid; idx < 1152; idx += 256) {
      int ic = idx / 9, t = idx - ic*9;
      wl[(e*9 + t)*WLS + ic] = wg[idx];
    }
  }
  __syncthreads();
  for (int it = 0; it < 18; ++it) {
    int flat = it*256 + tid;
    int bl = flat / 288;
    int slot = flat - bl*288;
    int t = slot >> 5, ic = (slot & 31) * 4;
    float4_ v = {0.f, 0.f, 0.f, 0.f};
    #pragma unroll
    for (int e = 0; e < E_; ++e) {
      float re = rl[bl*E_ + e];
      float4_ w = *(const float4_*)&wl[(e*9 + t)*WLS + ic];
      v[0] += re*w[0]; v[1] += re*w[1]; v[2] += re*w[2]; v[3] += re*w[3];
    }
    unsigned lo = (unsigned)f2bf(v[0]) | ((unsigned)f2bf(v[1]) << 16);
    unsigned hi = (unsigned)f2bf(v[2]) | ((unsigned)f2bf(v[3]) << 16);
    unsigned* dst = (unsigned*)&cwT[((size_t)((b0 + bl)*KK + t)*O_ + o)*I_ + ic];
    dst[0] = lo; dst[1] = hi;
  }
}

// ---------------- K4: halo-patch implicit GEMM, bf16 MFMA ----------------
// v5: WAVE-PRIVATE A staging, NO per-tap barriers (4 barriers/block total).
// Diagnosis (r6): per-tap __syncthreads lockstep all 8 waves/CU into the same
// resource phase (all-LDS-read then all-MFMA oscillation) -> both pipes ~30%.
// Each wave stages only the 64 A-rows it reads into a private ring-2 of 4 KB
// half-tap buffers (A LDS total 32 KB, same as before; waves 0,1 duplicate
// rows 0-63, cwT is L2-resident so HBM cost ~0). Self-paced with counted
// s_waitcnt vmcnt(4); waves drift and interleave LDS/MFMA across the SIMD.
// Within-wave WAR (stage overwrites buffer just read) closed by lgkmcnt(0)
// + sched_barrier(0) before the stage issue (rule-18 discipline).
__global__ __launch_bounds__(256, 2)
void k4_conv(const unsigned short* __restrict__ xp,
             const unsigned short* __restrict__ cwT,
             const float* __restrict__ r, const float* __restrict__ bias,
             float* __restrict__ out) {
  __shared__ __align__(16) unsigned short patch[PPIX*64];   // 43.5 KB, XOR-swizzled
  __shared__ __align__(16) unsigned short Alds[4*4096];     // 32 KB: [wave][buf2][64][32]
  __shared__ float cbs[128];

  const int tid  = threadIdx.x;
  const int lane = tid & 63;
  const int wave = tid >> 6;
  const int gr0 = blockIdx.x * NROW;      // first pixel row of tile
  const int m0  = blockIdx.y * 128;
  const int b   = blockIdx.z;

  if (tid < 128) {
    float s = 0.f;
    #pragma unroll
    for (int e = 0; e < 8; ++e) s += r[b*8 + e]*bias[e*O_ + m0 + tid];
    cbs[tid] = s;
  }

  const int q = lane >> 4, l16 = lane & 15;
  const int wm0 = (wave >> 1) * 64;
  const int wn0 = (wave & 1) * 112;

  // ---- A staging geometry (wave-private half-tap buffer [64][32], XOR slot swizzle) ----
  // slot s of row r holds ic-chunk q = s ^ ((r>>1)&3); staged as base+lane*16B.
  const int arow = lane >> 2;                              // 0..15
  const int aq8  = ((lane & 3) ^ ((lane >> 3) & 3)) * 8;   // source chunk offset (elems)
  int aS[4];
  #pragma unroll
  for (int j = 0; j < 4; ++j)
    aS[j] = (m0 + wm0 + j*16 + arow)*I_ + aq8;
  const unsigned short* cwb = cwT + (size_t)b*KK*OI;
  unsigned short* aldst = &Alds[wave*4096 + lane*8];       // lane term = HW lane*16B

  // read offsets: af[f] at row (f*16+l16), slot q^((l16>>1)&3)
  const int l16h = (l16 >> 1) & 3;
  int ar[4];
  #pragma unroll
  for (int f = 0; f < 4; ++f)
    ar[f] = wave*4096 + (f*16 + l16)*32 + ((q ^ l16h)*8);

  int bg[7];
  #pragma unroll
  for (int g = 0; g < 7; ++g) {
    int p = wn0 + g*16 + l16;
    int rr_ = p / 56;
    bg[g] = rr_*58 + (p - rr_*56);
  }

  float4_ acc[4][7];
  #pragma unroll
  for (int f = 0; f < 4; ++f)
    #pragma unroll
    for (int g = 0; g < 7; ++g) acc[f][g] = (float4_){0.f, 0.f, 0.f, 0.f};

  const unsigned short* xpb = xp + (size_t)((b*HP + gr0)*HP)*I_;

#define STAGE_A(TAP, SH, BUF) {                                               \
    const unsigned short* asrc = cwb + (size_t)(TAP)*OI + iccofs + (SH)*32;   \
    _Pragma("unroll")                                                         \
    for (int j = 0; j < 4; ++j)                                               \
      gload16(asrc + aS[j], aldst + (BUF)*2048 + j*512);                      \
  }

// phase: vmcnt(VM) [stage(i) landed] -> ds_reads -> lgkm drain -> stage(i+2) -> MFMA
#define PHASE_CORE(BUF, TOFF, SH, VM, DOSTAGE, STAP, SSH)                     \
  asm volatile("s_waitcnt vmcnt(" VM ")" ::: "memory");                       \
  {                                                                           \
    short8 af[4], bfr[7];                                                     \
    _Pragma("unroll")                                                         \
    for (int f = 0; f < 4; ++f)                                               \
      af[f] = *(const short8*)&Alds[ar[f] + (BUF)*2048];                      \
    _Pragma("unroll")                                                         \
    for (int g = 0; g < 7; ++g) {                                             \
      int pp = bg[g] + (TOFF);                                                \
      bfr[g] = *(const short8*)&patch[pp*64 + ((((SH)*4 + q) ^ (pp & 7))*8)]; \
    }                                                                         \
    asm volatile("s_waitcnt lgkmcnt(0)" ::: "memory");                        \
    __builtin_amdgcn_sched_barrier(0);                                        \
    if (DOSTAGE) { STAGE_A(STAP, SSH, BUF) }                                  \
    __builtin_amdgcn_s_setprio(1);                                            \
    _Pragma("unroll")                                                         \
    for (int f = 0; f < 4; ++f)                                               \
      _Pragma("unroll")                                                       \
      for (int g = 0; g < 7; ++g)                                             \
        acc[f][g] = __builtin_amdgcn_mfma_f32_16x16x32_bf16(af[f], bfr[g],    \
                                                            acc[f][g], 0,0,0);\
    __builtin_amdgcn_s_setprio(0);                                            \
  }

// 18 half-tap phases per ic-chunk; ring-2 bufs; stage 2 phases ahead.
#define DO_CHUNK(ICCOFS)                                                      \
  __syncthreads();  /* all waves done with previous patch + A bufs */         \
  for (int it = 0; it < 11; ++it) {                                           \
    int c = it*256 + tid;                                                     \
    if (c < PPIX*8) {                                                         \
      int pp = c >> 3, k8 = c & 7;                                            \
      gload16(xpb + (size_t)pp*I_ + (ICCOFS) + ((k8 ^ (pp & 7))*8),           \
              &patch[c*8]);                                                   \
    }                                                                         \
  }                                                                           \
  {                                                                           \
    const int iccofs = (ICCOFS);                                              \
    STAGE_A(0, 0, 0)                                                          \
    STAGE_A(0, 1, 1)                                                          \
    __syncthreads();  /* drains patch + first A stages, publishes patch */    \
    PHASE_CORE(0, 0,   0, "4", 1, 1, 0)                                       \
    PHASE_CORE(1, 0,   1, "4", 1, 1, 1)                                       \
    PHASE_CORE(0, 1,   0, "4", 1, 2, 0)                                       \
    PHASE_CORE(1, 1,   1, "4", 1, 2, 1)                                       \
    PHASE_CORE(0, 2,   0, "4", 1, 3, 0)                                       \
    PHASE_CORE(1, 2,   1, "4", 1, 3, 1)                                       \
    PHASE_CORE(0, 58,  0, "4", 1, 4, 0)                                       \
    PHASE_CORE(1, 58,  1, "4", 1, 4, 1)                                       \
    PHASE_CORE(0, 59,  0, "4", 1, 5, 0)                                       \
    PHASE_CORE(1, 59,  1, "4", 1, 5, 1)                                       \
    PHASE_CORE(0, 60,  0, "4", 1, 6, 0)                                       \
    PHASE_CORE(1, 60,  1, "4", 1, 6, 1)                                       \
    PHASE_CORE(0, 116, 0, "4", 1, 7, 0)                                       \
    PHASE_CORE(1, 116, 1, "4", 1, 7, 1)                                       \
    PHASE_CORE(0, 117, 0, "4", 1, 8, 0)                                       \
    PHASE_CORE(1, 117, 1, "4", 1, 8, 1)                                       \
    PHASE_CORE(0, 118, 0, "4", 0, 0, 0)                                       \
    PHASE_CORE(1, 118, 1, "0", 0, 0, 0)                                       \
  }

  DO_CHUNK(0)
  DO_CHUNK(64)

#undef DO_CHUNK
#undef PHASE_CORE
#undef STAGE_A

  // epilogue: D row(m)=quad*4+reg, col(n)=lane&15
  const size_t obase = (size_t)(b*O_ + m0)*HW + gr0*W_;
  #pragma unroll
  for (int g = 0; g < 7; ++g) {
    int p = wn0 + g*16 + l16;          // tile-local pixel, always < 224
    #pragma unroll
    for (int f = 0; f < 4; ++f) {
      #pragma unroll
      for (int v = 0; v < 4; ++v) {
        int ml = wm0 + f*16 + q*4 + v;
        out[obase + (size_t)ml*HW + p] = acc[f][g][v] + cbs[ml];
      }
    }
  }
}

extern "C" void kernel_launch(void* const* d_in, const int* in_sizes, int n_in,
                              void* d_out, int out_size, void* d_ws, size_t ws_size,
                              hipStream_t stream) {
  const float* x      = (const float*)d_in[0];
  const float* weight = (const float*)d_in[1];
  const float* bias   = (const float*)d_in[2];
  const float* w1     = (const float*)d_in[3];
  const float* b1     = (const float*)d_in[4];
  const float* w2     = (const float*)d_in[5];
  const float* b2     = (const float*)d_in[6];
  float* out = (float*)d_out;
  char* ws = (char*)d_ws;

  unsigned short* xp     = (unsigned short*)(ws);
  float*          ppart  = (float*)(ws + POOL_OFF);
  float*          rr     = (float*)(ws + R_OFF);
  unsigned short* cwT    = (unsigned short*)(ws + CWT_OFF);

  k1_pool_pack<<<dim3(H_, B_), 256, 0, stream>>>(x, xp, ppart);
  k2_route<<<B_, 128, 0, stream>>>(ppart, w1, b1, w2, b2, rr);
  k3_combine<<<dim3(O_, 2), 256, 0, stream>>>(weight, rr, cwT);
  k4_conv<<<dim3(H_/NROW, 2, B_), 256, 0, stream>>>(xp, cwT, rr, bias, out);
}

// Round 8
// 262.070 us; speedup vs baseline: 1.2435x; 1.2435x over previous
//
#include <hip/hip_runtime.h>

#define E_ 8
#define O_ 256
#define I_ 128
#define B_ 32
#define H_ 56
#define W_ 56
#define HP 58
#define HW (H_*W_)
#define KK 9
#define OI (O_*I_)
#define HID 32

#define NROW 4          // pixel rows per n-tile
#define NPIX 224        // NROW*56
#define PPIX 348        // (NROW+2)*58 patch pixels

typedef __attribute__((ext_vector_type(8))) short short8;
typedef __attribute__((ext_vector_type(4))) float float4_;

// ws layout (bytes)
#define XP_ELEMS (B_*HP*HP*I_)                   // padded NHWC bf16
#define POOL_OFF ((size_t)XP_ELEMS*2)            // 27,557,888
#define R_OFF    (POOL_OFF + (size_t)B_*H_*I_*4) // pooled: only 16 KB used
#define CWT_OFF  (R_OFF + (size_t)B_*E_*4)

__device__ __forceinline__ unsigned short f2bf(float f) {
  union { float f; unsigned u; } v; v.f = f;
  unsigned r = v.u + 0x7FFFu + ((v.u >> 16) & 1u);
  return (unsigned short)(r >> 16);
}

__device__ __forceinline__ void gload16(const unsigned short* g, unsigned short* l) {
  __builtin_amdgcn_global_load_lds(
      (const __attribute__((address_space(1))) unsigned int*)g,
      (__attribute__((address_space(3))) unsigned int*)l, 16, 0, 0);
}

// ---------------- K1: NCHW f32 -> padded NHWC bf16, + pooled channel sums ----------------
// pooled[b][ic] accumulated via atomicAdd (pooled memset'd by host each launch).
__global__ void k1_pool_pack(const float* __restrict__ x,
                             unsigned short* __restrict__ xp,
                             float* __restrict__ pooled) {
  __shared__ float lds[I_*57];
  const int h = blockIdx.x, b = blockIdx.y, tid = threadIdx.x;
  const float* xb = x + (size_t)b*I_*HW + h*W_;
  for (int idx = tid; idx < I_*14; idx += 256) {
    int ic = idx / 14, w4 = (idx - ic*14)*4;
    float4_ v = *(const float4_*)(xb + (size_t)ic*HW + w4);
    lds[ic*57 + w4 + 0] = v[0];
    lds[ic*57 + w4 + 1] = v[1];
    lds[ic*57 + w4 + 2] = v[2];
    lds[ic*57 + w4 + 3] = v[3];
  }
  __syncthreads();
  if (tid < I_) {
    float s = 0.f;
    #pragma unroll 8
    for (int wv = 0; wv < W_; ++wv) s += lds[tid*57 + wv];
    atomicAdd(&pooled[b*I_ + tid], s);
  }
  unsigned short* xrow = xp + ((size_t)(b*HP + h + 1)*HP)*I_;
  for (int idx2 = tid; idx2 < W_*(I_/2); idx2 += 256) {
    int wv = idx2 >> 6, ic2 = idx2 & 63;
    unsigned short u0 = f2bf(lds[(ic2*2)*57 + wv]);
    unsigned short u1 = f2bf(lds[(ic2*2+1)*57 + wv]);
    *(unsigned*)&xrow[(wv+1)*I_ + ic2*2] = (unsigned)u0 | ((unsigned)u1 << 16);
  }
  if (tid < I_) {           // pad columns 0 and 57 of this row
    xrow[0*I_ + tid] = 0;
    xrow[57*I_ + tid] = 0;
  }
  if (h == 0) {             // pad row 0
    unsigned short* r0 = xp + (size_t)(b*HP)*HP*I_;
    for (int idx = tid; idx < HP*I_; idx += 256) r0[idx] = 0;
  }
  if (h == H_-1) {          // pad row 57
    unsigned short* r57 = xp + (size_t)((b*HP + 57)*HP)*I_;
    for (int idx = tid; idx < HP*I_; idx += 256) r57[idx] = 0;
  }
}

// ---------------- K3: routing MLP (fused, was k2) + expert combine -> cwT ----------------
// Single pass over all 32 b (weight read ONCE). Each block recomputes routing
// from pooled (cheap, L2-hot). Block 0 publishes r for k4's bias combine.
#define WLS 132   // padded stride (132 % 32 = 4 -> conflict-free float4 reads)
__global__ void k3_combine(const float* __restrict__ weight,
                           const float* __restrict__ pooled,
                           const float* __restrict__ w1, const float* __restrict__ b1,
                           const float* __restrict__ w2, const float* __restrict__ b2,
                           unsigned short* __restrict__ cwT, float* __restrict__ rr) {
  __shared__ float wl[E_*9*WLS];   // 38,016 B
  __shared__ float pl[B_][I_+1];   // 16.5 KB
  __shared__ float hb[B_][HID+1];  // 4.2 KB
  __shared__ float lgf[B_][9];     // 1.2 KB
  __shared__ float rl[B_*E_];      // 1 KB
  const int o = blockIdx.x, tid = threadIdx.x;

  // stage expert weights transposed [e][t][ic] + pooled
  for (int e = 0; e < E_; ++e) {
    const float* wg = weight + (size_t)(e*O_ + o)*1152;
    for (int idx = tid; idx < 1152; idx += 256) {
      int ic = idx / 9, t = idx - ic*9;
      wl[(e*9 + t)*WLS + ic] = wg[idx];
    }
  }
  for (int i = tid; i < B_*I_; i += 256)
    pl[i >> 7][i & 127] = pooled[i] * (1.f/HW);
  __syncthreads();

  // hidden: thread (b = tid>>3, j = tid&7) computes units j*4..j*4+3
  {
    const int b = tid >> 3, j = tid & 7;
    float hacc[4];
    #pragma unroll
    for (int u = 0; u < 4; ++u) hacc[u] = b1[j*4 + u];
    for (int i = 0; i < I_; ++i) {
      float p = pl[b][i];
      #pragma unroll
      for (int u = 0; u < 4; ++u) hacc[u] += p * w1[(j*4 + u)*I_ + i];
    }
    #pragma unroll
    for (int u = 0; u < 4; ++u) hb[b][j*4 + u] = hacc[u] > 0.f ? hacc[u] : 0.f;
  }
  __syncthreads();
  // logits: thread (b, e = tid&7)
  {
    const int b = tid >> 3, e = tid & 7;
    float s = b2[e];
    #pragma unroll
    for (int j = 0; j < HID; ++j) s += hb[b][j] * w2[e*HID + j];
    lgf[b][e] = s;
  }
  __syncthreads();
  if ((tid & 7) == 0) {   // softmax per b
    const int b = tid >> 3;
    float m = lgf[b][0];
    #pragma unroll
    for (int e = 1; e < E_; ++e) m = fmaxf(m, lgf[b][e]);
    float ex[E_], sum = 0.f;
    #pragma unroll
    for (int e = 0; e < E_; ++e) { ex[e] = expf(lgf[b][e] - m); sum += ex[e]; }
    float inv = 1.f/sum;
    #pragma unroll
    for (int e = 0; e < E_; ++e) rl[b*E_ + e] = ex[e]*inv;
  }
  __syncthreads();
  if (o == 0) rr[tid] = rl[tid];   // publish r (256 = B_*E_ values) for k4

  // combine: 32 b x 9 t x 32 ic4 = 9216 = 36*256
  for (int it = 0; it < 36; ++it) {
    int flat = it*256 + tid;
    int bl = flat / 288;
    int slot = flat - bl*288;
    int t = slot >> 5, ic = (slot & 31) * 4;
    float4_ v = {0.f, 0.f, 0.f, 0.f};
    #pragma unroll
    for (int e = 0; e < E_; ++e) {
      float re = rl[bl*E_ + e];
      float4_ w = *(const float4_*)&wl[(e*9 + t)*WLS + ic];
      v[0] += re*w[0]; v[1] += re*w[1]; v[2] += re*w[2]; v[3] += re*w[3];
    }
    unsigned lo = (unsigned)f2bf(v[0]) | ((unsigned)f2bf(v[1]) << 16);
    unsigned hi = (unsigned)f2bf(v[2]) | ((unsigned)f2bf(v[3]) << 16);
    unsigned* dst = (unsigned*)&cwT[((size_t)(bl*KK + t)*O_ + o)*I_ + ic];
    dst[0] = lo; dst[1] = hi;
  }
}

// ---------------- K4: halo-patch implicit GEMM, bf16 MFMA ----------------
// ROUND-6 STRUCTURE, UNCHANGED (proven 77.5 us; MFMA-busy = dense-peak floor).
// r5/r7 lessons: no register headroom beyond compiler schedule at acc=112 AGPRs.
__global__ __launch_bounds__(256, 2)
void k4_conv(const unsigned short* __restrict__ xp,
             const unsigned short* __restrict__ cwT,
             const float* __restrict__ r, const float* __restrict__ bias,
             float* __restrict__ out) {
  __shared__ __align__(16) unsigned short patch[PPIX*64];     // 43.5 KB, XOR-swizzled
  __shared__ __align__(16) unsigned short ldsA[2][128*64];    // 2 x 16 KB
  __shared__ float cbs[128];

  const int tid  = threadIdx.x;
  const int lane = tid & 63;
  const int wave = tid >> 6;
  const int gr0 = blockIdx.x * NROW;      // first pixel row of tile
  const int m0  = blockIdx.y * 128;
  const int b   = blockIdx.z;

  if (tid < 128) {
    float s = 0.f;
    #pragma unroll
    for (int e = 0; e < 8; ++e) s += r[b*8 + e]*bias[e*O_ + m0 + tid];
    cbs[tid] = s;
  }

  const int q = lane >> 4, l16 = lane & 15;
  const int lrow = lane >> 3, chunk = (lane & 7) ^ lrow;
  const int wm0 = (wave >> 1) * 64;
  const int wn0 = (wave & 1) * 112;

  int ainv[4];
  #pragma unroll
  for (int j = 0; j < 4; ++j)
    ainv[j] = (wave*32 + j*8 + lrow)*I_ + chunk*8;
  int rowA[4];
  #pragma unroll
  for (int f = 0; f < 4; ++f) rowA[f] = (wm0 + f*16 + l16)*64;
  int xq[2];
  #pragma unroll
  for (int s = 0; s < 2; ++s) xq[s] = ((s*4 + q) ^ (l16 & 7))*8;
  int bg[7];
  #pragma unroll
  for (int g = 0; g < 7; ++g) {
    int p = wn0 + g*16 + l16;
    int rr_ = p / 56;
    bg[g] = rr_*58 + (p - rr_*56);
  }

  float4_ acc[4][7];
  #pragma unroll
  for (int f = 0; f < 4; ++f)
    #pragma unroll
    for (int g = 0; g < 7; ++g) acc[f][g] = (float4_){0.f, 0.f, 0.f, 0.f};

  const unsigned short* xpb = xp + (size_t)((b*HP + gr0)*HP)*I_;

  for (int icc = 0; icc < 2; ++icc) {
    __syncthreads();   // patch + both A buffers free (implicit vmcnt drain)
    // stage halo patch: async global->LDS, source pre-swizzled (m173 pattern).
    for (int it = 0; it < 11; ++it) {
      int c = it*256 + tid;
      if (c < PPIX*8) {
        int pp = c >> 3, k8 = c & 7;
        gload16(xpb + (size_t)pp*I_ + icc*64 + ((k8 ^ (pp & 7))*8),
                &patch[c*8]);
      }
    }
    // stage A for tap 0
    {
      const unsigned short* ab = cwT + ((size_t)(b*KK)*O_ + m0)*I_ + icc*64;
      #pragma unroll
      for (int j = 0; j < 4; ++j)
        gload16(ab + ainv[j], &ldsA[0][(wave*32 + j*8)*64]);
    }
    for (int tap = 0; tap < 9; ++tap) {
      __syncthreads();   // publishes A[tap] (and patch on tap==0)
      if (tap < 8) {     // prefetch A[tap+1] into the other buffer
        const unsigned short* ab = cwT + ((size_t)(b*KK + tap + 1)*O_ + m0)*I_ + icc*64;
        #pragma unroll
        for (int j = 0; j < 4; ++j)
          gload16(ab + ainv[j], &ldsA[(tap + 1) & 1][(wave*32 + j*8)*64]);
      }
      const unsigned short* At = ldsA[tap & 1];
      const int kh = tap / 3, kw = tap - kh*3;
      const int toff = kh*58 + kw;
      #pragma unroll
      for (int s = 0; s < 2; ++s) {
        short8 af[4], bfr[7];
        #pragma unroll
        for (int f = 0; f < 4; ++f) af[f] = *(const short8*)&At[rowA[f] + xq[s]];
        #pragma unroll
        for (int g = 0; g < 7; ++g) {
          int pp = bg[g] + toff;
          bfr[g] = *(const short8*)&patch[pp*64 + (((s*4 + q) ^ (pp & 7))*8)];
        }
        __builtin_amdgcn_s_setprio(1);
        #pragma unroll
        for (int f = 0; f < 4; ++f)
          #pragma unroll
          for (int g = 0; g < 7; ++g)
            acc[f][g] = __builtin_amdgcn_mfma_f32_16x16x32_bf16(af[f], bfr[g], acc[f][g], 0, 0, 0);
        __builtin_amdgcn_s_setprio(0);
      }
    }
  }

  // epilogue: D row(m)=quad*4+reg, col(n)=lane&15
  const size_t obase = (size_t)(b*O_ + m0)*HW + gr0*W_;
  #pragma unroll
  for (int g = 0; g < 7; ++g) {
    int p = wn0 + g*16 + l16;          // tile-local pixel, always < 224
    #pragma unroll
    for (int f = 0; f < 4; ++f) {
      #pragma unroll
      for (int v = 0; v < 4; ++v) {
        int ml = wm0 + f*16 + q*4 + v;
        out[obase + (size_t)ml*HW + p] = acc[f][g][v] + cbs[ml];
      }
    }
  }
}

extern "C" void kernel_launch(void* const* d_in, const int* in_sizes, int n_in,
                              void* d_out, int out_size, void* d_ws, size_t ws_size,
                              hipStream_t stream) {
  const float* x      = (const float*)d_in[0];
  const float* weight = (const float*)d_in[1];
  const float* bias   = (const float*)d_in[2];
  const float* w1     = (const float*)d_in[3];
  const float* b1     = (const float*)d_in[4];
  const float* w2     = (const float*)d_in[5];
  const float* b2     = (const float*)d_in[6];
  float* out = (float*)d_out;
  char* ws = (char*)d_ws;

  unsigned short* xp     = (unsigned short*)(ws);
  float*          pooled = (float*)(ws + POOL_OFF);
  float*          rr     = (float*)(ws + R_OFF);
  unsigned short* cwT    = (unsigned short*)(ws + CWT_OFF);

  hipMemsetAsync(pooled, 0, (size_t)B_*I_*sizeof(float), stream);
  k1_pool_pack<<<dim3(H_, B_), 256, 0, stream>>>(x, xp, pooled);
  k3_combine<<<O_, 256, 0, stream>>>(weight, pooled, w1, b1, w2, b2, cwT, rr);
  k4_conv<<<dim3(H_/NROW, 2, B_), 256, 0, stream>>>(xp, cwT, rr, bias, out);
}